// Round 6
// baseline (352.608 us; speedup 1.0000x reference)
//
#include <hip/hip_runtime.h>
#include <hip/hip_fp16.h>

#define N_NODES 100000
#define KK 5
#define CC 16
#define EE 3200000
#define NXCC 8

#define NB 16                // row buckets
#define ROWS_PB 6250         // N_NODES / NB
#define WCAP 384             // entries per (chunk,bucket) staging window (+3.7 sigma)
#define WPAD 385             // LDS stride: bucket bases land on distinct banks
#define BPB2 32              // accum slices per bucket (16*32 = 512 blocks, 2/CU)
#define CHUNK 5120           // edges per scatter chunk
#define NCHUNK 3125          // 3125 * 5120 = 16,000,000
#define BLK_PER_K 625        // EE / CHUNK
#define SGRID 256            // persistent scatter blocks (1/CU)
#define BSTRIDE 1081344      // per-bucket dense capacity: mean 1M, sigma~968, +84 sigma

__device__ __forceinline__ int xcc_id() {
    int x;
    asm volatile("s_getreg_b32 %0, hwreg(HW_REG_XCC_ID)" : "=s"(x));
    return x & (NXCC - 1);
}

// Kernel 1: Zt[k*N + n] (fp32, for fallback) and Zh[k*N + n] (fp16, for scatter)
__global__ void compute_z_kernel(const float* __restrict__ X,
                                 const float* __restrict__ h,
                                 float* __restrict__ Zt,
                                 __half* __restrict__ Zh) {
    int n = blockIdx.x * blockDim.x + threadIdx.x;
    if (n >= N_NODES) return;
    const float4* Xr = (const float4*)(X + (size_t)n * CC);
    float4 x0 = Xr[0], x1 = Xr[1], x2 = Xr[2], x3 = Xr[3];
    float xv[CC] = {x0.x, x0.y, x0.z, x0.w, x1.x, x1.y, x1.z, x1.w,
                    x2.x, x2.y, x2.z, x2.w, x3.x, x3.y, x3.z, x3.w};
#pragma unroll
    for (int k = 0; k < KK; ++k) {
        float acc = 0.0f;
#pragma unroll
        for (int c = 0; c < CC; ++c) acc += xv[c] * h[c * KK + k];
        Zt[k * N_NODES + n] = acc;
        Zh[k * N_NODES + n] = __float2half_rn(acc);
    }
}

// Phase A (R10): gather-path levers are exhausted (R3 2x occupancy: null,
// R4 L1 bypass: -3%, R5 65% request removal: -7%). Back half is ~220us
// CONSTANT across 4 accum restructures -> accum ~190us is the real monster.
// This round: dense per-bucket output streams. Scatter reserves space with
// ONE global cursor atomic per (chunk,bucket) -- 50k total -- then flushes
// coalesced. Removes windowed layout entirely so accum becomes a pure
// dense stream (controlled test: ds_add count unchanged).
template<int SN>
__global__ __launch_bounds__(512, 2)
void scatter_lds_kernel(const int* __restrict__ rows,
                        const int* __restrict__ cols,
                        const float* __restrict__ vals,
                        const __half* __restrict__ Zh,
                        unsigned int* __restrict__ dense,
                        int* __restrict__ gcursor,
                        float* __restrict__ spill) {
    extern __shared__ char dynlds[];
    __half*       zsl = (__half*)dynlds;                   // SN*2 bytes
    unsigned int* buf = (unsigned int*)(dynlds + (size_t)SN * 2);  // NB*WPAD*4
    __shared__ int lcnt[NB];
    __shared__ int gbase[NB];
    int tid = threadIdx.x;
    int bid = blockIdx.x;
    int w0 = (int)(((long long)NCHUNK * bid) / SGRID);
    int w1 = (int)(((long long)NCHUNK * (bid + 1)) / SGRID);

    int klast = -1;
    for (int w = w0; w < w1; ++w) {
        int k = w / BLK_PER_K;                             // block-uniform
        const __half* Zk_h = Zh + (size_t)k * N_NODES;
        if (SN > 0 && k != klast) {
            __syncthreads();                               // prior chunk done with zsl
            const float4* zsrc = (const float4*)Zk_h;      // 16B-aligned
            float4*       zdst = (float4*)dynlds;
#pragma unroll
            for (int i = 0; i < SN / 4096; ++i)            // SN/8 float4s, 512 thr
                zdst[tid + i * 512] = zsrc[tid + i * 512];
            klast = k;
            __syncthreads();
        }
        if (tid < NB) lcnt[tid] = 0;
        __syncthreads();

        int cbase = w * CHUNK;
        // ---- inputs: 9 vector loads in flight ----
        int e0 = cbase + tid * 4;
        int e1 = cbase + 2048 + tid * 4;
        int e2 = cbase + 4096 + tid * 2;
        int4   r0 = *(const int4*)(rows + e0);
        int4   c0 = *(const int4*)(cols + e0);
        float4 v0 = *(const float4*)(vals + e0);
        int4   r1 = *(const int4*)(rows + e1);
        int4   c1 = *(const int4*)(cols + e1);
        float4 v1 = *(const float4*)(vals + e1);
        int2   r2 = *(const int2*)(rows + e2);
        int2   c2 = *(const int2*)(cols + e2);
        float2 v2 = *(const float2*)(vals + e2);

        int   cc[10] = {c0.x, c0.y, c0.z, c0.w, c1.x, c1.y, c1.z, c1.w, c2.x, c2.y};
        int   rr[10] = {r0.x, r0.y, r0.z, r0.w, r1.x, r1.y, r1.z, r1.w, r2.x, r2.y};
        float vv[10] = {v0.x, v0.y, v0.z, v0.w, v1.x, v1.y, v1.z, v1.w, v2.x, v2.y};

        // ---- gathers: LDS slice hit (~65%) or residual L2 request ----
        float z[10];
#pragma unroll
        for (int i = 0; i < 10; ++i) {
            unsigned c = (unsigned)cc[i];
            __half hz;
            if (SN > 0 && c < (unsigned)SN) hz = zsl[c];
            else                            hz = Zk_h[c];
            z[i] = __half2float(hz);
        }

        // ---- LDS position allocation ----
        int pos[10];
#pragma unroll
        for (int i = 0; i < 10; ++i) {
            int b = rr[i] / ROWS_PB;                       // magic-mul
            pos[i] = atomicAdd(&lcnt[b], 1);
        }

        // ---- pack + stage ----
#pragma unroll
        for (int i = 0; i < 10; ++i) {
            int b = rr[i] / ROWS_PB;
            float cb = vv[i] * z[i];
            int p = pos[i];
            if (p < WCAP) {
                unsigned int packed =
                    ((unsigned)(rr[i] - b * ROWS_PB) << 16) |
                    (unsigned)__half_as_ushort(__float2half_rn(cb));
                buf[b * WPAD + p] = packed;
            } else {
                unsafeAtomicAdd(&spill[rr[i]], cb);        // exact, ~never taken
            }
        }
        __syncthreads();

        // ---- reserve dense space: 1 global atomic per (chunk,bucket) ----
        if (tid < NB) {
            int cnt = min(lcnt[tid], WCAP);
            gbase[tid] = atomicAdd(&gcursor[tid], cnt);
        }
        __syncthreads();

        // ---- coalesced flush into dense per-bucket stream ----
#pragma unroll 1
        for (int b = 0; b < NB; ++b) {
            int cnt  = min(lcnt[b], WCAP);                 // wave-uniform
            int base = gbase[b];
            int lim  = min(cnt, max(0, BSTRIDE - base));   // overflow guard
            unsigned int* dst = dense + (size_t)b * BSTRIDE + base;
            if (tid < lim) dst[tid] = buf[b * WPAD + tid];
            for (int i = lim + tid; i < cnt; i += 512) {   // ~never taken
                unsigned int ev = buf[b * WPAD + i];
                unsafeAtomicAdd(&spill[b * ROWS_PB + (int)(ev >> 16)],
                                __half2float(__ushort_as_half((unsigned short)(ev & 0xFFFFu))));
            }
        }
        __syncthreads();                                   // buf/lcnt reuse next chunk
    }
}

// Phase B (R10): pure dense stream -- no window counts, no predication, no
// padding over-read. Each block (b,s) owns a contiguous 1/32 of bucket b's
// dense stream; 8 loads in flight, then the ds_add burst. If this is still
// ~150+us the bottleneck is the ds_add_f32 RMW rate itself, not structure.
__global__ __launch_bounds__(512, 2)
void accum_kernel(const unsigned int* __restrict__ dense,
                  const int* __restrict__ gcursor,
                  float* __restrict__ partials) {
    __shared__ float acc[ROWS_PB];                         // 25 KB
    int b = blockIdx.x >> 5;
    int s = blockIdx.x & 31;
    int tid = threadIdx.x;
    int cnt = min(gcursor[b], BSTRIDE);
    int lo = (int)((long long)cnt * s / BPB2);
    int hi = (int)((long long)cnt * (s + 1) / BPB2);
    for (int i = tid; i < ROWS_PB; i += 512) acc[i] = 0.0f;
    __syncthreads();

    const unsigned int* src = dense + (size_t)b * BSTRIDE;
    int i = lo + tid;
    for (; i + 512 * 7 < hi; i += 512 * 8) {
        unsigned int e[8];
#pragma unroll
        for (int j = 0; j < 8; ++j) e[j] = src[i + 512 * j];
#pragma unroll
        for (int j = 0; j < 8; ++j)
            atomicAdd(&acc[e[j] >> 16],
                      __half2float(__ushort_as_half((unsigned short)(e[j] & 0xFFFFu))));
    }
    for (; i < hi; i += 512) {
        unsigned int e = src[i];
        atomicAdd(&acc[e >> 16],
                  __half2float(__ushort_as_half((unsigned short)(e & 0xFFFFu))));
    }
    __syncthreads();
    float* dst = partials + (size_t)blockIdx.x * ROWS_PB;
    for (int i2 = tid; i2 < ROWS_PB; i2 += 512) dst[i2] = acc[i2];
}

// y[n] = spill[n] + sum over BPB2 partial slices of n's bucket
__global__ void reduce_kernel(const float* __restrict__ partials,
                              const float* __restrict__ spill,
                              float* __restrict__ y) {
    int n = blockIdx.x * blockDim.x + threadIdx.x;
    if (n >= N_NODES) return;
    int b = n / ROWS_PB, loc = n - b * ROWS_PB;
    const float* p = partials + (size_t)(b * BPB2) * ROWS_PB + loc;
    float acc = spill[n];
#pragma unroll 8
    for (int s = 0; s < BPB2; ++s) acc += p[(size_t)s * ROWS_PB];
    y[n] = acc;
}

// ---------- fallback path: far-atomic scatter, used if ws too small ----
__global__ void edge_kernel_atomic(const int* __restrict__ rows,
                                   const int* __restrict__ cols,
                                   const float* __restrict__ vals,
                                   const float* __restrict__ Zt,
                                   float* __restrict__ yrep) {
    int t = blockIdx.x * blockDim.x + threadIdx.x;
    int base = t * 4;
    if (base >= KK * EE) return;
    int k = base / EE;
    const float* Zk = Zt + (size_t)k * N_NODES;
    float* y = yrep + (size_t)xcc_id() * N_NODES;
    int4 r = *(const int4*)(rows + base);
    int4 c = *(const int4*)(cols + base);
    float4 v = *(const float4*)(vals + base);
    unsafeAtomicAdd(&y[r.x], v.x * Zk[c.x]);
    unsafeAtomicAdd(&y[r.y], v.y * Zk[c.y]);
    unsafeAtomicAdd(&y[r.z], v.z * Zk[c.z]);
    unsafeAtomicAdd(&y[r.w], v.w * Zk[c.w]);
}

__global__ void reduce8_kernel(const float* __restrict__ yrep, float* __restrict__ y) {
    int n = blockIdx.x * blockDim.x + threadIdx.x;
    if (n >= N_NODES) return;
    float acc = 0.0f;
#pragma unroll
    for (int r = 0; r < NXCC; ++r) acc += yrep[(size_t)r * N_NODES + n];
    y[n] = acc;
}

extern "C" void kernel_launch(void* const* d_in, const int* in_sizes, int n_in,
                              void* d_out, int out_size, void* d_ws, size_t ws_size,
                              hipStream_t stream) {
    const float* X    = (const float*)d_in[0];
    const int*   rows = (const int*)  d_in[1];
    const int*   cols = (const int*)  d_in[2];
    const float* vals = (const float*)d_in[3];
    const float* h    = (const float*)d_in[4];
    float* y = (float*)d_out;

    char* ws = (char*)d_ws;
    float*  Zt = (float*)ws;                                   //  2,000,000 B
    size_t zh_off      = 2000000;                              //  1,000,000 B
    size_t cursor_off  = 3000000;                              //        256 B
    size_t spill_off   = 3000256;                              //    400,000 B
    size_t dense_off   = 3400256;
    size_t dense_sz    = (size_t)NB * BSTRIDE * 4;             //  69,206,016 B
    size_t partial_off = dense_off + dense_sz;                 // 72,606,272
    size_t partial_sz  = (size_t)NB * BPB2 * ROWS_PB * 4;      //  12,800,000 B
    size_t need = partial_off + partial_sz;                    // ~85.4 MB
    __half* Zh = (__half*)(ws + zh_off);

    {   // Z = X @ h  (Zt layout [k][n], fp32 + fp16)
        int threads = 256;
        int blocks  = (N_NODES + threads - 1) / threads;
        compute_z_kernel<<<blocks, threads, 0, stream>>>(X, h, Zt, Zh);
    }

    if (ws_size >= need) {
        int*          gcursor  = (int*)(ws + cursor_off);
        float*        spill    = (float*)(ws + spill_off);
        unsigned int* dense    = (unsigned int*)(ws + dense_off);
        float*        partials = (float*)(ws + partial_off);
        hipMemsetAsync(ws + cursor_off, 0, 256 + 400000, stream);  // cursors + spill

        // runtime probe: largest launchable Z-slice (capture-legal queries only)
        static int g_sn = -1;
        const size_t stag = (size_t)NB * WPAD * 4;             // 24,640 B
        if (g_sn < 0) {
            g_sn = 0;
            int nb = 0;
            hipFuncSetAttribute((const void*)scatter_lds_kernel<65536>,
                                hipFuncAttributeMaxDynamicSharedMemorySize,
                                (int)(65536 * 2 + stag));
            if (hipOccupancyMaxActiveBlocksPerMultiprocessor(
                    &nb, scatter_lds_kernel<65536>, 512, 65536 * 2 + stag) == hipSuccess
                && nb >= 1) g_sn = 65536;
            if (g_sn == 0) {
                nb = 0;
                hipFuncSetAttribute((const void*)scatter_lds_kernel<49152>,
                                    hipFuncAttributeMaxDynamicSharedMemorySize,
                                    (int)(49152 * 2 + stag));
                if (hipOccupancyMaxActiveBlocksPerMultiprocessor(
                        &nb, scatter_lds_kernel<49152>, 512, 49152 * 2 + stag) == hipSuccess
                    && nb >= 1) g_sn = 49152;
            }
            if (g_sn == 0) {
                nb = 0;
                hipFuncSetAttribute((const void*)scatter_lds_kernel<32768>,
                                    hipFuncAttributeMaxDynamicSharedMemorySize,
                                    (int)(32768 * 2 + stag));
                if (hipOccupancyMaxActiveBlocksPerMultiprocessor(
                        &nb, scatter_lds_kernel<32768>, 512, 32768 * 2 + stag) == hipSuccess
                    && nb >= 1) g_sn = 32768;
            }
        }
        size_t dyn = (size_t)g_sn * 2 + stag;
        switch (g_sn) {
        case 65536:
            scatter_lds_kernel<65536><<<SGRID, 512, dyn, stream>>>(
                rows, cols, vals, Zh, dense, gcursor, spill);
            break;
        case 49152:
            scatter_lds_kernel<49152><<<SGRID, 512, dyn, stream>>>(
                rows, cols, vals, Zh, dense, gcursor, spill);
            break;
        case 32768:
            scatter_lds_kernel<32768><<<SGRID, 512, dyn, stream>>>(
                rows, cols, vals, Zh, dense, gcursor, spill);
            break;
        default:
            scatter_lds_kernel<0><<<SGRID, 512, dyn, stream>>>(
                rows, cols, vals, Zh, dense, gcursor, spill);
            break;
        }

        accum_kernel<<<NB * BPB2, 512, 0, stream>>>(dense, gcursor, partials);
        {
            int threads = 256;
            int blocks  = (N_NODES + threads - 1) / threads;
            reduce_kernel<<<blocks, threads, 0, stream>>>(partials, spill, y);
        }
    } else {
        // fallback: far-atomic path
        float* yrep = (float*)(ws + spill_off);
        hipMemsetAsync(yrep, 0, (size_t)NXCC * N_NODES * sizeof(float), stream);
        {
            int threads = 256;
            int blocks = ((KK * EE) / 4 + threads - 1) / threads;
            edge_kernel_atomic<<<blocks, threads, 0, stream>>>(rows, cols, vals, Zt, yrep);
        }
        {
            int threads = 256;
            int blocks  = (N_NODES + threads - 1) / threads;
            reduce8_kernel<<<blocks, threads, 0, stream>>>(yrep, y);
        }
    }
}